// Round 1
// baseline (186.337 us; speedup 1.0000x reference)
//
#include <hip/hip_runtime.h>
#include <math.h>

typedef short short8 __attribute__((ext_vector_type(8)));
typedef float float4_t __attribute__((ext_vector_type(4)));
typedef unsigned uint2_t __attribute__((ext_vector_type(2)));
typedef unsigned short ushort_t;

#define BH   32
#define N_   2048
#define D_   64
#define NCH  32
#define LDP  72
#define KV_ELEMS (BH * N_ * D_)
// d_ws: Kf [0,8M) | Vf [8M,16M) | msk [16M,16.5M)
#define OFF_VF  (KV_ELEMS * 2)
#define OFF_MSK (KV_ELEMS * 4)
#define QSCALE 0.18033688f      // 0.125*log2(e): exp(s/8) == exp2(s*QSCALE)

__device__ __forceinline__ unsigned pack_bf16(float a, float b) {
  union { float f; unsigned u; } ua{a}, ub{b};
  return __builtin_amdgcn_perm(ub.u + 0x8000u, ua.u + 0x8000u, 0x07060302u);
}

// ---------------- prep (r8-verified, unchanged): fragment-linear Kf/Vf + bitmask ----------------
__global__ __launch_bounds__(256) void prep_kernel(
    const float* __restrict__ K, const float* __restrict__ V,
    const int* __restrict__ adj, ushort_t* __restrict__ Kf,
    ushort_t* __restrict__ Vf, unsigned long long* __restrict__ msk) {
  __shared__ __align__(16) float Tc[64 * 68];
  const int blk = blockIdx.x, t = threadIdx.x;

  if (blk < 2048) {
    const bool isK = blk < 1024;
    const int b = isK ? blk : blk - 1024;
    const float* src = (isK ? K : V) + (b >> 5) * (N_ * D_) + (b & 31) * 64 * D_;
#pragma unroll
    for (int i = 0; i < 4; ++i) {
      int idx = i * 256 + t;
      int row = idx >> 4, c4 = (idx & 15) * 4;
      *(float4_t*)&Tc[row * 68 + c4] = *(const float4_t*)(src + row * D_ + c4);
    }
    __syncthreads();
    ushort_t* dst = (isK ? Kf : Vf) + b * 4096;
#pragma unroll
    for (int e = 0; e < 2; ++e) {
      int u = t * 2 + e;
      int g = u >> 6, lane = u & 63;
      int ks = g >> 2, quad = lane >> 4, l16 = lane & 15;
      float v[8];
      if (isK) {
        int nt = g & 3;
        const float* rp = &Tc[(nt * 16 + l16) * 68 + ks * 32 + quad * 8];
        float4_t a = *(const float4_t*)(rp);
        float4_t bq = *(const float4_t*)(rp + 4);
#pragma unroll
        for (int j = 0; j < 4; ++j) { v[j] = a[j]; v[4 + j] = bq[j]; }
      } else {
        int dt = g & 3, d = dt * 16 + l16;
#pragma unroll
        for (int j = 0; j < 8; ++j) {
          int key = 16 * (j & 3) + ks * 8 + quad * 2 + (j >> 2);
          v[j] = Tc[key * 68 + d];
        }
      }
      union { short8 s; unsigned u4[4]; } h;
      h.u4[0] = pack_bf16(v[0], v[1]); h.u4[1] = pack_bf16(v[2], v[3]);
      h.u4[2] = pack_bf16(v[4], v[5]); h.u4[3] = pack_bf16(v[6], v[7]);
      *(short8*)(dst + u * 8) = h.s;
    }
  } else {
    const int row = (blk - 2048) * 4 + (t >> 6);
    const int lane = t & 63;
    unsigned long long keep = 0;
#pragma unroll 8
    for (int i = 0; i < 32; ++i) {
      int a = adj[row * N_ + i * 64 + lane];
      unsigned long long b = __ballot(a > 0);
      if (lane == i) keep = b;
    }
    if (lane < 32) msk[row * 32 + lane] = keep;
  }
}

// -------- main v2: 16 rows/wave, 1024 blocks (4/CU, 4 waves/SIMD), barrier-free --------
__global__ __launch_bounds__(256, 4) void attn_main(
    const float* __restrict__ Q, const ushort_t* __restrict__ Kf,
    const ushort_t* __restrict__ Vf, const unsigned long long* __restrict__ msk,
    float* __restrict__ O) {
  __shared__ __align__(16) ushort_t lds_p[4][16 * LDP];  // wave-private P, 9216 B

  const int t    = threadIdx.x;
  const int w    = t >> 6;
  const int lane = t & 63;
  const int quad = lane >> 4;
  const int l16  = lane & 15;
  const int bh   = blockIdx.x & (BH - 1);
  const int qt   = blockIdx.x >> 5;          // 0..31
  const int base = bh * (N_ * D_);
  const int qrow0 = qt * 64 + w * 16;        // 16 rows per wave

  const ushort_t* Kfb = Kf + (bh * 32) * 4096;
  const ushort_t* Vfb = Vf + (bh * 32) * 4096;
  const unsigned long long* mr = msk + (qrow0 + quad * 4) * 32;

  // Q fragments, QSCALE folded (A-layout m=l16, k=ks*32+quad*8+j)
  short8 qf[2];
#pragma unroll
  for (int ks = 0; ks < 2; ++ks) {
    const float* qp = Q + base + (qrow0 + l16) * D_ + ks * 32 + quad * 8;
    float4_t f0 = *(const float4_t*)(qp);
    float4_t f1 = *(const float4_t*)(qp + 4);
    union { short8 s; unsigned u[4]; } h;
    h.u[0] = pack_bf16(f0[0] * QSCALE, f0[1] * QSCALE);
    h.u[1] = pack_bf16(f0[2] * QSCALE, f0[3] * QSCALE);
    h.u[2] = pack_bf16(f1[0] * QSCALE, f1[1] * QSCALE);
    h.u[3] = pack_bf16(f1[2] * QSCALE, f1[3] * QSCALE);
    qf[ks] = h.s;
  }

  // constant ones B-fragment (bf16 1.0) for lsum-via-MFMA
  short8 ones;
#pragma unroll
  for (int j = 0; j < 8; ++j) ones[j] = (short)0x3F80;

  float4_t oacc[4];    // O, C-layout
  float4_t osum;       // row-sums of masked P (all 16 cols identical)
#pragma unroll
  for (int dt = 0; dt < 4; ++dt) oacc[dt] = (float4_t){0.f, 0.f, 0.f, 0.f};
  osum = (float4_t){0.f, 0.f, 0.f, 0.f};

  const int fo = lane * 8;   // lane-linear fragment offset (16B/lane coalesced)

  for (int c = 0; c < NCH; ++c) {
    const ushort_t* kg = Kfb + c * 4096;
    const ushort_t* vg = Vfb + c * 4096;

    // issue all chunk loads up front: K frags, V frags, mask words
    short8 kfr[2][4], vfr[2][4];
#pragma unroll
    for (int ks = 0; ks < 2; ++ks)
#pragma unroll
      for (int nt = 0; nt < 4; ++nt) {
        kfr[ks][nt] = *(const short8*)(kg + (ks * 4 + nt) * 512 + fo);
        vfr[ks][nt] = *(const short8*)(vg + (ks * 4 + nt) * 512 + fo);
      }
    unsigned long long mw[4];
#pragma unroll
    for (int r = 0; r < 4; ++r) mw[r] = mr[r * 32 + c];

    // ---- S-MFMAs -> mask+exp -> P to wave-private LDS ----
    float4_t sacc[4];
#pragma unroll
    for (int nt = 0; nt < 4; ++nt) sacc[nt] = (float4_t){0.f, 0.f, 0.f, 0.f};
#pragma unroll
    for (int ks = 0; ks < 2; ++ks)
#pragma unroll
      for (int nt = 0; nt < 4; ++nt)
        sacc[nt] = __builtin_amdgcn_mfma_f32_16x16x32_bf16(qf[ks], kfr[ks][nt], sacc[nt], 0, 0, 0);

#pragma unroll
    for (int r = 0; r < 4; ++r) {
      unsigned long long sh = mw[r] >> l16;
      unsigned lo = (unsigned)sh, hi = (unsigned)(sh >> 32);
      float p0 = (lo & 1u)       ? exp2f(sacc[0][r]) : 0.f;
      float p1 = (lo & 0x10000u) ? exp2f(sacc[1][r]) : 0.f;
      float p2 = (hi & 1u)       ? exp2f(sacc[2][r]) : 0.f;
      float p3 = (hi & 0x10000u) ? exp2f(sacc[3][r]) : 0.f;
      uint2_t d2;
      d2.x = pack_bf16(p0, p1);
      d2.y = pack_bf16(p2, p3);
      *(uint2_t*)&lds_p[w][(quad * 4 + r) * LDP + (l16 << 2)] = d2;
    }
    // no barrier: wave-private, ordered by lgkmcnt

    // ---- O += P V ; osum += P * ones ----
#pragma unroll
    for (int ks = 0; ks < 2; ++ks) {
      short8 pf = *(const short8*)&lds_p[w][l16 * LDP + ks * 32 + quad * 8];
#pragma unroll
      for (int dt = 0; dt < 4; ++dt)
        oacc[dt] = __builtin_amdgcn_mfma_f32_16x16x32_bf16(pf, vfr[ks][dt], oacc[dt], 0, 0, 0);
      osum = __builtin_amdgcn_mfma_f32_16x16x32_bf16(pf, ones, osum, 0, 0, 0);
    }
  }

  // ---- epilogue: rowsum already per-lane in osum (all cols equal) ----
#pragma unroll
  for (int r = 0; r < 4; ++r) {
    float inv = 1.f / osum[r];
    int qi = qrow0 + quad * 4 + r;
#pragma unroll
    for (int dt = 0; dt < 4; ++dt)
      O[base + qi * D_ + dt * 16 + l16] = oacc[dt][r] * inv;
  }
}

extern "C" void kernel_launch(void* const* d_in, const int* in_sizes, int n_in,
                              void* d_out, int out_size, void* d_ws, size_t ws_size,
                              hipStream_t stream) {
  const float* Q  = (const float*)d_in[0];
  const float* K  = (const float*)d_in[1];
  const float* V  = (const float*)d_in[2];
  const int* adj  = (const int*)d_in[3];
  float* O        = (float*)d_out;
  ushort_t* Kf    = (ushort_t*)d_ws;
  ushort_t* Vf    = (ushort_t*)((char*)d_ws + OFF_VF);
  unsigned long long* msk = (unsigned long long*)((char*)d_ws + OFF_MSK);

  prep_kernel<<<2560, 256, 0, stream>>>(K, V, adj, Kf, Vf, msk);
  attn_main<<<1024, 256, 0, stream>>>(Q, Kf, Vf, msk, O);   // 4096 waves, 16/CU
}

// Round 2
// 170.797 us; speedup vs baseline: 1.0910x; 1.0910x over previous
//
#include <hip/hip_runtime.h>
#include <math.h>

typedef short short8 __attribute__((ext_vector_type(8)));
typedef float float4_t __attribute__((ext_vector_type(4)));
typedef unsigned uint2_t __attribute__((ext_vector_type(2)));
typedef unsigned short ushort_t;

#define BH   32
#define N_   2048
#define D_   64
#define NCH  32
#define LDP  72
#define KV_ELEMS (BH * N_ * D_)
// d_ws: Kf [0,8M) | Vf [8M,16M) | msk [16M,16.5M)
#define OFF_VF  (KV_ELEMS * 2)
#define OFF_MSK (KV_ELEMS * 4)
#define QSCALE 0.18033688f      // 0.125*log2(e): exp(s/8) == exp2(s*QSCALE)

__device__ __forceinline__ unsigned pack_bf16(float a, float b) {
  union { float f; unsigned u; } ua{a}, ub{b};
  return __builtin_amdgcn_perm(ub.u + 0x8000u, ua.u + 0x8000u, 0x07060302u);
}

__device__ __forceinline__ void gload_lds16(const ushort_t* g, ushort_t* l) {
  // async global->LDS, 16B/lane, lane-linear dest (fragment-linear layout)
  __builtin_amdgcn_global_load_lds(
      (const __attribute__((address_space(1))) unsigned int*)(g),
      (__attribute__((address_space(3))) unsigned int*)(l), 16, 0, 0);
}

// ---------------- prep (r8-verified, unchanged): fragment-linear Kf/Vf + bitmask ----------------
__global__ __launch_bounds__(256) void prep_kernel(
    const float* __restrict__ K, const float* __restrict__ V,
    const int* __restrict__ adj, ushort_t* __restrict__ Kf,
    ushort_t* __restrict__ Vf, unsigned long long* __restrict__ msk) {
  __shared__ __align__(16) float Tc[64 * 68];
  const int blk = blockIdx.x, t = threadIdx.x;

  if (blk < 2048) {
    const bool isK = blk < 1024;
    const int b = isK ? blk : blk - 1024;
    const float* src = (isK ? K : V) + (b >> 5) * (N_ * D_) + (b & 31) * 64 * D_;
#pragma unroll
    for (int i = 0; i < 4; ++i) {
      int idx = i * 256 + t;
      int row = idx >> 4, c4 = (idx & 15) * 4;
      *(float4_t*)&Tc[row * 68 + c4] = *(const float4_t*)(src + row * D_ + c4);
    }
    __syncthreads();
    ushort_t* dst = (isK ? Kf : Vf) + b * 4096;
#pragma unroll
    for (int e = 0; e < 2; ++e) {
      int u = t * 2 + e;
      int g = u >> 6, lane = u & 63;
      int ks = g >> 2, quad = lane >> 4, l16 = lane & 15;
      float v[8];
      if (isK) {
        int nt = g & 3;
        const float* rp = &Tc[(nt * 16 + l16) * 68 + ks * 32 + quad * 8];
        float4_t a = *(const float4_t*)(rp);
        float4_t bq = *(const float4_t*)(rp + 4);
#pragma unroll
        for (int j = 0; j < 4; ++j) { v[j] = a[j]; v[4 + j] = bq[j]; }
      } else {
        int dt = g & 3, d = dt * 16 + l16;
#pragma unroll
        for (int j = 0; j < 8; ++j) {
          int key = 16 * (j & 3) + ks * 8 + quad * 2 + (j >> 2);
          v[j] = Tc[key * 68 + d];
        }
      }
      union { short8 s; unsigned u4[4]; } h;
      h.u4[0] = pack_bf16(v[0], v[1]); h.u4[1] = pack_bf16(v[2], v[3]);
      h.u4[2] = pack_bf16(v[4], v[5]); h.u4[3] = pack_bf16(v[6], v[7]);
      *(short8*)(dst + u * 8) = h.s;
    }
  } else {
    const int row = (blk - 2048) * 4 + (t >> 6);
    const int lane = t & 63;
    unsigned long long keep = 0;
#pragma unroll 8
    for (int i = 0; i < 32; ++i) {
      int a = adj[row * N_ + i * 64 + lane];
      unsigned long long b = __ballot(a > 0);
      if (lane == i) keep = b;
    }
    if (lane < 32) msk[row * 32 + lane] = keep;
  }
}

// -------- main v3: 8 waves/block share LDS-staged K/V (dbuf), 16 rows/wave --------
__global__ __launch_bounds__(512) void attn_main(
    const float* __restrict__ Q, const ushort_t* __restrict__ Kf,
    const ushort_t* __restrict__ Vf, const unsigned long long* __restrict__ msk,
    float* __restrict__ O) {
  __shared__ __align__(16) ushort_t kv[2][8192];        // [K 8KB | V 8KB] x2, 32KB
  __shared__ __align__(16) ushort_t lds_p[8][16 * LDP]; // wave-private P, 18KB

  const int t    = threadIdx.x;
  const int w    = t >> 6;                   // 0..7
  const int lane = t & 63;
  const int quad = lane >> 4;
  const int l16  = lane & 15;
  const int bh   = blockIdx.x & (BH - 1);
  const int qt   = blockIdx.x >> 5;          // 0..15
  const int base = bh * (N_ * D_);
  const int qrow0 = qt * 128 + w * 16;       // 16 rows per wave, 128 per block

  const ushort_t* Kfb = Kf + (bh * 32) * 4096;
  const ushort_t* Vfb = Vf + (bh * 32) * 4096;
  const unsigned long long* mr = msk + (qrow0 + quad * 4) * 32;

  // Q fragments, QSCALE folded (A-layout m=l16, k=ks*32+quad*8+j)
  short8 qf[2];
#pragma unroll
  for (int ks = 0; ks < 2; ++ks) {
    const float* qp = Q + base + (qrow0 + l16) * D_ + ks * 32 + quad * 8;
    float4_t f0 = *(const float4_t*)(qp);
    float4_t f1 = *(const float4_t*)(qp + 4);
    union { short8 s; unsigned u[4]; } h;
    h.u[0] = pack_bf16(f0[0] * QSCALE, f0[1] * QSCALE);
    h.u[1] = pack_bf16(f0[2] * QSCALE, f0[3] * QSCALE);
    h.u[2] = pack_bf16(f1[0] * QSCALE, f1[1] * QSCALE);
    h.u[3] = pack_bf16(f1[2] * QSCALE, f1[3] * QSCALE);
    qf[ks] = h.s;
  }

  // constant ones B-fragment (bf16 1.0) for lsum-via-MFMA
  short8 ones;
#pragma unroll
  for (int j = 0; j < 8; ++j) ones[j] = (short)0x3F80;

  float4_t oacc[4];
  float4_t osum;
#pragma unroll
  for (int dt = 0; dt < 4; ++dt) oacc[dt] = (float4_t){0.f, 0.f, 0.f, 0.f};
  osum = (float4_t){0.f, 0.f, 0.f, 0.f};

  const int fo = lane * 8;   // lane-linear fragment offset (16B/lane)

  // cooperative stage of chunk c into kv[nb]: wave w moves bytes [w*2KB, +2KB)
  // (w<4 -> K chunk, w>=4 -> V chunk); 2 x global_load_lds dwordx4 per wave
#define STAGE(nb, c)                                                          \
  do {                                                                        \
    const ushort_t* _s = (w < 4 ? Kfb + (c)*4096 + w * 1024                   \
                                : Vfb + (c)*4096 + (w - 4) * 1024) + lane * 8;\
    ushort_t* _d = &kv[nb][w * 1024];                                         \
    gload_lds16(_s, _d);                                                      \
    gload_lds16(_s + 512, _d + 512);                                          \
  } while (0)

  STAGE(0, 0);   // prologue

#pragma unroll 2
  for (int c = 0; c < NCH; ++c) {
    const int cur = c & 1;
    // implicit vmcnt(0)+lgkmcnt(0) drain: stage(c) landed for ALL waves
    __syncthreads();

    // mask words first (so their wait is vmcnt(16), stage stays in flight)
    unsigned long long mw[4];
#pragma unroll
    for (int r = 0; r < 4; ++r) mw[r] = mr[r * 32 + c];

    if (c + 1 < NCH) STAGE(cur ^ 1, c + 1);

    const ushort_t* kb = &kv[cur][0];
    const ushort_t* vb = &kv[cur][4096];

    // ---- S-MFMAs from LDS fragments ----
    float4_t sacc[4];
#pragma unroll
    for (int nt = 0; nt < 4; ++nt) sacc[nt] = (float4_t){0.f, 0.f, 0.f, 0.f};
#pragma unroll
    for (int ks = 0; ks < 2; ++ks)
#pragma unroll
      for (int nt = 0; nt < 4; ++nt) {
        short8 kfr = *(const short8*)(kb + (ks * 4 + nt) * 512 + fo);
        sacc[nt] = __builtin_amdgcn_mfma_f32_16x16x32_bf16(qf[ks], kfr, sacc[nt], 0, 0, 0);
      }

    // ---- mask + exp -> P to wave-private LDS ----
#pragma unroll
    for (int r = 0; r < 4; ++r) {
      unsigned long long sh = mw[r] >> l16;
      unsigned lo = (unsigned)sh, hi = (unsigned)(sh >> 32);
      float p0 = (lo & 1u)       ? exp2f(sacc[0][r]) : 0.f;
      float p1 = (lo & 0x10000u) ? exp2f(sacc[1][r]) : 0.f;
      float p2 = (hi & 1u)       ? exp2f(sacc[2][r]) : 0.f;
      float p3 = (hi & 0x10000u) ? exp2f(sacc[3][r]) : 0.f;
      uint2_t d2;
      d2.x = pack_bf16(p0, p1);
      d2.y = pack_bf16(p2, p3);
      *(uint2_t*)&lds_p[w][(quad * 4 + r) * LDP + (l16 << 2)] = d2;
    }
    // no barrier: wave-private, ordered by lgkmcnt

    // ---- O += P V ; osum += P * ones ----
#pragma unroll
    for (int ks = 0; ks < 2; ++ks) {
      short8 pf = *(const short8*)&lds_p[w][l16 * LDP + ks * 32 + quad * 8];
#pragma unroll
      for (int dt = 0; dt < 4; ++dt) {
        short8 vfr = *(const short8*)(vb + (ks * 4 + dt) * 512 + fo);
        oacc[dt] = __builtin_amdgcn_mfma_f32_16x16x32_bf16(pf, vfr, oacc[dt], 0, 0, 0);
      }
      osum = __builtin_amdgcn_mfma_f32_16x16x32_bf16(pf, ones, osum, 0, 0, 0);
    }
  }

  // ---- epilogue: rowsum already per-lane in osum (all cols equal) ----
#pragma unroll
  for (int r = 0; r < 4; ++r) {
    float inv = 1.f / osum[r];
    int qi = qrow0 + quad * 4 + r;
#pragma unroll
    for (int dt = 0; dt < 4; ++dt)
      O[base + qi * D_ + dt * 16 + l16] = oacc[dt][r] * inv;
  }
}

extern "C" void kernel_launch(void* const* d_in, const int* in_sizes, int n_in,
                              void* d_out, int out_size, void* d_ws, size_t ws_size,
                              hipStream_t stream) {
  const float* Q  = (const float*)d_in[0];
  const float* K  = (const float*)d_in[1];
  const float* V  = (const float*)d_in[2];
  const int* adj  = (const int*)d_in[3];
  float* O        = (float*)d_out;
  ushort_t* Kf    = (ushort_t*)d_ws;
  ushort_t* Vf    = (ushort_t*)((char*)d_ws + OFF_VF);
  unsigned long long* msk = (unsigned long long*)((char*)d_ws + OFF_MSK);

  prep_kernel<<<2560, 256, 0, stream>>>(K, V, adj, Kf, Vf, msk);
  attn_main<<<512, 512, 0, stream>>>(Q, Kf, Vf, msk, O);   // 4096 waves, 16/CU
}